// Round 3
// baseline (859.203 us; speedup 1.0000x reference)
//
#include <hip/hip_runtime.h>

#define KS 51
#define RAD 25
#define DIM 128
#define HW 64
#define TROWS 32           // output rows per block (image split in halves)
#define XROWS 82           // TROWS + 2*RAD
#define XSTRIDE 116        // 29 x 16B, odd in 16B units -> conflict-free b128
#define WSTRIDE 52         // weight row stride (13 x float4), col 51 zeroed

// Map signed offset o in [-25,25] to peripheral index 0..12.
// coords = [0,1,2,4,8,16,25]; quantise = largest coord <= |o|.
__device__ __forceinline__ int qidx(int o) {
  int a = o < 0 ? -o : o;
  int r;
  if (a >= 25)      r = 6;
  else if (a >= 16) r = 5;
  else if (a >= 8)  r = 4;
  else if (a >= 4)  r = 3;
  else if (a >= 2)  r = 2;
  else              r = a;   // 0 -> 0, 1 -> 1
  return o < 0 ? 6 - r : 6 + r;
}

__launch_bounds__(256, 3)
__global__ void dwconv(const float* __restrict__ x,
                       const float* __restrict__ comp,
                       const float* __restrict__ kpe,
                       float* __restrict__ out) {
  __shared__ float xs[XROWS * XSTRIDE];   // 38,048 B
  __shared__ float wlds[KS * WSTRIDE];    // 10,608 B  (total 48.7 KB -> 3 blk/CU)
  const int bid  = blockIdx.x;            // img*2 + half
  const int img  = bid >> 1;
  const int half = bid & 1;
  const int c    = img & (DIM - 1);
  const int tid  = threadIdx.x;

  // ---- zero the padded x tile ----
  const float4 z4 = make_float4(0.f, 0.f, 0.f, 0.f);
  for (int i = tid; i < XROWS * XSTRIDE / 4; i += 256)
    *(float4*)&xs[i * 4] = z4;
  __syncthreads();

  // ---- fill x center: xs[lr][25+col] = x[r0+lr][col] ----
  const float* __restrict__ ximg = x + (size_t)img * (HW * HW);
  const int r0 = half * TROWS - RAD;
  {
    const int q = tid & 3;                 // 16-col chunk
    for (int lr = tid >> 2; lr < XROWS; lr += 64) {
      const int rg = r0 + lr;
      if (0 <= rg && rg < HW) {
        const float* src = ximg + rg * HW + q * 16;
        float* dst = &xs[lr * XSTRIDE + RAD + q * 16];
#pragma unroll
        for (int i = 0; i < 4; ++i) {
          const float4 v = *(const float4*)&src[4 * i];
          dst[4 * i + 0] = v.x; dst[4 * i + 1] = v.y;
          dst[4 * i + 2] = v.z; dst[4 * i + 3] = v.w;
        }
      }
    }
  }

  // ---- expand this channel's dense 51x51 kernel into LDS ----
  const float* __restrict__ crow = comp + c * 169;   // 13*13
  for (int t = tid; t < KS * WSTRIDE; t += 256) {
    const int ki = t / WSTRIDE, kj = t - ki * WSTRIDE;
    float v = 0.f;
    if (kj < KS)
      v = crow[qidx(ki - RAD) * 13 + qidx(kj - RAD)] + kpe[ki * KS + kj];
    wlds[t] = v;
  }
  __syncthreads();

  // ---- main stencil: thread = (row 0..31, 8-col strip) ----
  const int row = tid >> 3;
  const int cb  = (tid & 7) << 3;

  float acc[8];
#pragma unroll
  for (int j = 0; j < 8; ++j) acc[j] = 0.f;

  for (int ki = 0; ki < KS; ++ki) {
    const float* xr = &xs[(row + ki) * XSTRIDE + cb];
    float W[60];
#pragma unroll
    for (int t = 0; t < 15; ++t)
      *(float4*)&W[4 * t] = *(const float4*)&xr[4 * t];   // ds_read_b128, conflict-free

    const float* wr = &wlds[ki * WSTRIDE];
#pragma unroll
    for (int k4 = 0; k4 < 13; ++k4) {
      const float4 wv = *(const float4*)&wr[4 * k4];      // uniform broadcast
#pragma unroll
      for (int j = 0; j < 8; ++j) acc[j] = fmaf(wv.x, W[4 * k4 + 0 + j], acc[j]);
#pragma unroll
      for (int j = 0; j < 8; ++j) acc[j] = fmaf(wv.y, W[4 * k4 + 1 + j], acc[j]);
#pragma unroll
      for (int j = 0; j < 8; ++j) acc[j] = fmaf(wv.z, W[4 * k4 + 2 + j], acc[j]);
#pragma unroll
      for (int j = 0; j < 8; ++j) acc[j] = fmaf(wv.w, W[4 * k4 + 3 + j], acc[j]);
    }
  }

  float* orow = out + (size_t)img * (HW * HW) + (half * TROWS + row) * HW + cb;
  *(float4*)&orow[0] = make_float4(acc[0], acc[1], acc[2], acc[3]);
  *(float4*)&orow[4] = make_float4(acc[4], acc[5], acc[6], acc[7]);
}

extern "C" void kernel_launch(void* const* d_in, const int* in_sizes, int n_in,
                              void* d_out, int out_size, void* d_ws, size_t ws_size,
                              hipStream_t stream) {
  const float* x    = (const float*)d_in[0];
  const float* comp = (const float*)d_in[1];
  const float* kpe  = (const float*)d_in[2];
  float* out        = (float*)d_out;

  // 16*128 images x 2 half-tiles, fully stateless single kernel
  dwconv<<<dim3(16 * DIM * 2), dim3(256), 0, stream>>>(x, comp, kpe, out);
}

// Round 4
// 517.222 us; speedup vs baseline: 1.6612x; 1.6612x over previous
//
#include <hip/hip_runtime.h>

#define KS 51
#define RAD 25
#define DIM 128
#define HW 64
#define XROWS 114          // 64 + 2*25
#define XSTRIDE 116        // 29 x 16B chunks per row (odd chunk count)
#define WSTRIDE 52         // weight row stride; col 51 zeroed

// Map signed offset o in [-25,25] to peripheral index 0..12.
// coords = [0,1,2,4,8,16,25]; quantise = largest coord <= |o|.
__device__ __forceinline__ int qidx(int o) {
  int a = o < 0 ? -o : o;
  int r;
  if (a >= 25)      r = 6;
  else if (a >= 16) r = 5;
  else if (a >= 8)  r = 4;
  else if (a >= 4)  r = 3;
  else if (a >= 2)  r = 2;
  else              r = a;   // 0 -> 0, 1 -> 1
  return o < 0 ? 6 - r : 6 + r;
}

__launch_bounds__(256, 2)
__global__ void dwconv(const float* __restrict__ x,
                       const float* __restrict__ comp,
                       const float* __restrict__ kpe,
                       float* __restrict__ out) {
  __shared__ float xs[XROWS * XSTRIDE];   // 52,896 B
  __shared__ float wlds[KS * WSTRIDE];    // 10,608 B
  const int img = blockIdx.x;             // b*128 + c
  const int c   = img & (DIM - 1);
  const int tid = threadIdx.x;

  // ---- zero padded tile (sequential float4 -> conflict-free) ----
  const float4 z4 = make_float4(0.f, 0.f, 0.f, 0.f);
  for (int i = tid; i < XROWS * XSTRIDE / 4; i += 256)
    *(float4*)&xs[i * 4] = z4;

  // ---- expand this channel's dense 51x51 kernel into LDS ----
  const float* __restrict__ crow = comp + c * 169;   // 13*13
  for (int t = tid; t < KS * WSTRIDE; t += 256) {
    const int ki = t / WSTRIDE, kj = t - ki * WSTRIDE;
    float v = 0.f;
    if (kj < KS)
      v = crow[qidx(ki - RAD) * 13 + qidx(kj - RAD)] + kpe[ki * KS + kj];
    wlds[t] = v;
  }
  __syncthreads();

  // ---- fill center: xs[25+r][25+col] = x[r][col] (one-time scalar writes) ----
  const float* __restrict__ ximg = x + (size_t)img * (HW * HW);
  {
    const int r = tid >> 2, q = tid & 3;
    const float* src = ximg + r * HW + q * 16;
    float* dst = &xs[(RAD + r) * XSTRIDE + RAD + q * 16];
#pragma unroll
    for (int i = 0; i < 4; ++i) {
      const float4 v = *(const float4*)&src[4 * i];
      dst[4 * i + 0] = v.x; dst[4 * i + 1] = v.y;
      dst[4 * i + 2] = v.z; dst[4 * i + 3] = v.w;
    }
  }
  __syncthreads();

  // ---- conflict-free lane mapping: row varies WITHIN each lane octet ----
  // position(16B) = 5*row_lo + 4*q16 + const (mod 8); row_lo spans 0..7 per
  // octet with odd multiplier 5 -> all 8 bank positions covered exactly once.
  const int lane   = tid & 63;
  const int wv_id  = tid >> 6;
  const int row_lo = lane & 7;
  const int q16    = (lane >> 3) & 3;
  const int row_hi = (lane >> 5) & 1;
  const int row    = row_lo + 8 * row_hi + 16 * wv_id;   // 0..63
  const int cb     = q16 << 4;                           // 0,16,32,48

  float acc[16];
#pragma unroll
  for (int j = 0; j < 16; ++j) acc[j] = 0.f;

#pragma unroll 1
  for (int ki = 0; ki < KS; ++ki) {
    const float* xr = &xs[(row + ki) * XSTRIDE + cb];
    float W[68];
#pragma unroll
    for (int t = 0; t < 17; ++t)
      *(float4*)&W[4 * t] = *(const float4*)&xr[4 * t];   // ds_read_b128

    const float* wr = &wlds[ki * WSTRIDE];
#pragma unroll
    for (int k4 = 0; k4 < 13; ++k4) {
      const float4 wv = *(const float4*)&wr[4 * k4];      // uniform broadcast
#pragma unroll
      for (int j = 0; j < 16; ++j) acc[j] = fmaf(wv.x, W[4 * k4 + 0 + j], acc[j]);
#pragma unroll
      for (int j = 0; j < 16; ++j) acc[j] = fmaf(wv.y, W[4 * k4 + 1 + j], acc[j]);
#pragma unroll
      for (int j = 0; j < 16; ++j) acc[j] = fmaf(wv.z, W[4 * k4 + 2 + j], acc[j]);
#pragma unroll
      for (int j = 0; j < 16; ++j) acc[j] = fmaf(wv.w, W[4 * k4 + 3 + j], acc[j]);
    }
  }

  float* orow = out + (size_t)img * (HW * HW) + row * HW + cb;
#pragma unroll
  for (int t = 0; t < 4; ++t)
    *(float4*)&orow[4 * t] =
        make_float4(acc[4 * t], acc[4 * t + 1], acc[4 * t + 2], acc[4 * t + 3]);
}

extern "C" void kernel_launch(void* const* d_in, const int* in_sizes, int n_in,
                              void* d_out, int out_size, void* d_ws, size_t ws_size,
                              hipStream_t stream) {
  const float* x    = (const float*)d_in[0];
  const float* comp = (const float*)d_in[1];
  const float* kpe  = (const float*)d_in[2];
  float* out        = (float*)d_out;

  dwconv<<<dim3(16 * DIM), dim3(256), 0, stream>>>(x, comp, kpe, out);
}

// Round 5
// 402.033 us; speedup vs baseline: 2.1371x; 1.2865x over previous
//
#include <hip/hip_runtime.h>

#define KS 51
#define RAD 25
#define DIM 128
#define HW 64
#define XR 114            // 64 + 2*25 padded rows
#define XC 120            // f16 cols/row: 240 B = 15 x 16B (odd -> conflict-free)
#define WSLOT 56          // u32 slots per ki row (52 used: A[26] then B[26])

typedef _Float16 h2 __attribute__((ext_vector_type(2)));

__device__ __forceinline__ h2 bc_h2(unsigned u) { return __builtin_bit_cast(h2, u); }
__device__ __forceinline__ unsigned bc_u32(h2 h) { return __builtin_bit_cast(unsigned, h); }

__device__ __forceinline__ float dot2(h2 a, h2 b, float c) {
#if __has_builtin(__builtin_amdgcn_fdot2)
  return __builtin_amdgcn_fdot2(a, b, c, false);   // 2 MACs, exact products, f32 acc
#else
  return fmaf((float)a.y, (float)b.y, fmaf((float)a.x, (float)b.x, c));
#endif
}

// coords = [0,1,2,4,8,16,25]; quantise = largest coord <= |o|; signed index 0..12
__device__ __forceinline__ int qidx(int o) {
  int a = o < 0 ? -o : o;
  int r;
  if (a >= 25)      r = 6;
  else if (a >= 16) r = 5;
  else if (a >= 8)  r = 4;
  else if (a >= 4)  r = 3;
  else if (a >= 2)  r = 2;
  else              r = a;
  return o < 0 ? 6 - r : 6 + r;
}

// POFF = window pair offset (0 for even-col waves, 1 for odd-col waves)
template <int POFF>
__device__ __forceinline__ void conv_rows(const _Float16* xrow, const unsigned* wrow,
                                          float acc[16]) {
#pragma unroll 1
  for (int ki = 0; ki < KS; ++ki) {
    h2 P[42];                                     // 84 f16 window (pairs)
    const uint4* w4 = (const uint4*)xrow;
#pragma unroll
    for (int t = 0; t < 10; ++t) {
      uint4 v = w4[t];
      P[4*t+0] = bc_h2(v.x); P[4*t+1] = bc_h2(v.y);
      P[4*t+2] = bc_h2(v.z); P[4*t+3] = bc_h2(v.w);
    }
    { uint2 v = ((const uint2*)xrow)[20]; P[40] = bc_h2(v.x); P[41] = bc_h2(v.y); }

    h2 Wt[26];                                    // this wave's parity table
#pragma unroll
    for (int t = 0; t < 13; ++t) {
      uint2 v = ((const uint2*)wrow)[t];          // uniform b64 broadcast
      Wt[2*t] = bc_h2(v.x); Wt[2*t+1] = bc_h2(v.y);
    }

#pragma unroll
    for (int m = 0; m < 16; ++m) {
      float a = acc[m];
#pragma unroll
      for (int t = 0; t < 26; ++t)
        a = dot2(P[m + POFF + t], Wt[t], a);      // all indices compile-time
      acc[m] = a;
    }
    xrow += XC;
    wrow += WSLOT;
  }
}

__launch_bounds__(256, 3)
__global__ void dwconv(const float* __restrict__ x, const float* __restrict__ comp,
                       const float* __restrict__ kpe, float* __restrict__ out) {
  __shared__ _Float16 xs[XR * XC];     // 27,360 B
  __shared__ unsigned wl[KS * WSLOT];  // 11,424 B   (total 38.8 KB)
  const int img = blockIdx.x;          // b*128 + c
  const int c   = img & (DIM - 1);
  const int tid = threadIdx.x;

  // ---- zero padded tile ----
  uint4 z; z.x = z.y = z.z = z.w = 0u;
  uint4* xs4 = (uint4*)xs;
  for (int i = tid; i < XR * XC * 2 / 16; i += 256) xs4[i] = z;
  __syncthreads();

  // ---- dense f16 weight pairs, both kj-parities, zero-padded ----
  // A[t] = (w[2t-1], w[2t])  slots 0..25 ;  B[t] = (w[2t], w[2t+1]) slots 26..51
  const float* __restrict__ crow = comp + c * 169;
  for (int idx = tid; idx < KS * 52; idx += 256) {
    const int ki = idx / 52, slot = idx - ki * 52;
    int kj0, kj1;
    if (slot < 26) { kj0 = 2 * slot - 1; kj1 = 2 * slot; }
    else           { const int b = slot - 26; kj0 = 2 * b; kj1 = 2 * b + 1; }
    const int qi13 = qidx(ki - RAD) * 13;
    float w0 = 0.f, w1 = 0.f;
    if (kj0 >= 0 && kj0 < KS) w0 = crow[qi13 + qidx(kj0 - RAD)] + kpe[ki * KS + kj0];
    if (kj1 < KS)             w1 = crow[qi13 + qidx(kj1 - RAD)] + kpe[ki * KS + kj1];
    h2 p; p.x = (_Float16)w0; p.y = (_Float16)w1;
    wl[ki * WSLOT + slot] = bc_u32(p);
  }

  // ---- fill center: LDS col l holds input col l-26 (left halo 26 -> 4B align) ----
  {
    const int r = tid >> 2, q = tid & 3;
    const float* src = x + (size_t)img * (HW * HW) + r * HW + q * 16;
    unsigned* dst = (unsigned*)&xs[(RAD + r) * XC + 26 + q * 16];
#pragma unroll
    for (int i = 0; i < 4; ++i) {
      const float4 v = ((const float4*)src)[i];
      h2 a; a.x = (_Float16)v.x; a.y = (_Float16)v.y;
      h2 b; b.x = (_Float16)v.z; b.y = (_Float16)v.w;
      dst[2 * i]     = bc_u32(a);
      dst[2 * i + 1] = bc_u32(b);
    }
  }
  __syncthreads();

  // ---- lane mapping: row_lo in octet (bank coverage), parity per-WAVE (uniform) ----
  const int lane = tid & 63, wv = tid >> 6;
  const int row_lo = lane & 7;
  const int s  = lane >> 3;                 // 3 bits: row_mid(2) | ch(1)
  const int ch = s >> 2;                    // 32-col half
  const int row = row_lo + 8 * (s & 3) + 32 * (wv & 1);   // 0..63
  const int par = wv >> 1;                  // wave-uniform column parity

  float acc[16];
#pragma unroll
  for (int m = 0; m < 16; ++m) acc[m] = 0.f;

  const _Float16* xrow = &xs[row * XC + ch * 32];
  const unsigned* wrow = wl + par * 26;
  if (par == 0) conv_rows<0>(xrow, wrow, acc);   // wave-uniform branch
  else          conv_rows<1>(xrow, wrow, acc);

  // ---- write 16 same-parity columns (stride 2) ----
  float* op = out + (size_t)img * (HW * HW) + row * HW + ch * 32 + par;
#pragma unroll
  for (int m = 0; m < 16; ++m) op[2 * m] = acc[m];
}

extern "C" void kernel_launch(void* const* d_in, const int* in_sizes, int n_in,
                              void* d_out, int out_size, void* d_ws, size_t ws_size,
                              hipStream_t stream) {
  const float* x    = (const float*)d_in[0];
  const float* comp = (const float*)d_in[1];
  const float* kpe  = (const float*)d_in[2];
  float* out        = (float*)d_out;

  dwconv<<<dim3(16 * DIM), dim3(256), 0, stream>>>(x, comp, kpe, out);
}